// Round 12
// baseline (481.720 us; speedup 1.0000x reference)
//
#include <hip/hip_runtime.h>
#include <cstdint>

#define L_ 4096
#define NC_ 512
#define CD_ 256
#define H_ 8
#define D_ 128
#define B_ 4
#define SCALE 0.08838834764831845f
#define TAU 3.0e-3f

typedef _Float16 f16x8 __attribute__((ext_vector_type(8)));
typedef _Float16 f16x4 __attribute__((ext_vector_type(4)));
typedef float f32x16 __attribute__((ext_vector_type(16)));
typedef float f32x4 __attribute__((ext_vector_type(4)));

// ---------------------------------------------------------------------------
// Kernel A (R11 verbatim, verified): d-split grid dim3(32,8,2).
// ---------------------------------------------------------------------------
__global__ __launch_bounds__(256) void kv_pre(
    const float* __restrict__ codes, const float* __restrict__ Wk,
    const float* __restrict__ Wv, _Float16* __restrict__ K16f,
    float* __restrict__ K32, float* __restrict__ V)
{
    __shared__ float clds[16][260];
    const int t = threadIdx.x, h = blockIdx.y, n0 = blockIdx.x * 16;
    const int dz = blockIdx.z;
    {
        #pragma unroll
        for (int i = 0; i < 4; ++i) {
            int j = t + i*256;
            int row = j >> 6, c4 = j & 63;
            *(float4*)&clds[row][c4*4] =
                *(const float4*)(codes + (size_t)(n0 + row)*CD_ + c4*4);
        }
    }
    __syncthreads();
    const int nl = t >> 4;
    const int dq = t & 15;
    const int d0 = dz*64 + dq*4;
    const int n  = n0 + nl;
    float ak0=0,ak1=0,ak2=0,ak3=0, av0=0,av1=0,av2=0,av3=0;
    const float4* wk4 = (const float4*)Wk;
    const float4* wv4 = (const float4*)Wv;
    for (int c = 0; c < CD_; c += 4) {
        float4 cv = *(const float4*)&clds[nl][c];
        #pragma unroll
        for (int u = 0; u < 4; ++u) {
            float cu = (u==0)?cv.x:(u==1)?cv.y:(u==2)?cv.z:cv.w;
            float4 wk = wk4[((size_t)(c+u)*H_ + h)*32 + (d0>>2)];
            float4 wv = wv4[((size_t)(c+u)*H_ + h)*32 + (d0>>2)];
            ak0 = fmaf(cu, wk.x, ak0); ak1 = fmaf(cu, wk.y, ak1);
            ak2 = fmaf(cu, wk.z, ak2); ak3 = fmaf(cu, wk.w, ak3);
            av0 = fmaf(cu, wv.x, av0); av1 = fmaf(cu, wv.y, av1);
            av2 = fmaf(cu, wv.z, av2); av3 = fmaf(cu, wv.w, av3);
        }
    }
    const size_t r32 = ((size_t)(h*NC_ + n))*D_ + d0;
    float4 sk; sk.x=ak0; sk.y=ak1; sk.z=ak2; sk.w=ak3;
    float4 sv; sv.x=av0; sv.y=av1; sv.z=av2; sv.w=av3;
    *(float4*)(K32 + r32) = sk;
    *(float4*)(V   + r32) = sv;
    f16x4 hk; hk[0]=(_Float16)ak0; hk[1]=(_Float16)ak1; hk[2]=(_Float16)ak2; hk[3]=(_Float16)ak3;
    const size_t a16 = ((size_t)((h*16 + (n>>5))*8 + (d0>>4))*64
                        + ((n&31) + ((d0>>3)&1)*32))*8 + (d0&7);
    *(f16x4*)(K16f + a16) = hk;
}

// ---------------------------------------------------------------------------
// Kernel B template: MODE 0 = R11 verbatim. MODE 1..5 duplicate exactly one
// phase (results kept alive, no CSE), still writing correct outputs.
//   1=q-phase x2   2=K ds_read x2   3=MFMA x2   4=top-3 x2   5=epilogue x2
// ---------------------------------------------------------------------------
#define GLD_LDS16(GP, LP)                                                      \
  __builtin_amdgcn_global_load_lds(                                            \
      (const __attribute__((address_space(1))) void*)(GP),                     \
      (__attribute__((address_space(3))) void*)(LP), 16, 0, 0)

#define WAIT_VM0    asm volatile("s_waitcnt vmcnt(0)" ::: "memory")
#define WAIT_LGKM   asm volatile("s_waitcnt lgkmcnt(0)" ::: "memory")

#define QSTAGE(RD, QS)                                                         \
  _Pragma("unroll")                                                            \
  for (int i_ = 0; i_ < 4; ++i_) {                                             \
    const float* sp_ = xb + (size_t)((RD)*32 + i_*8 + (lane>>3))*L_            \
                          + l0w + (lane&7)*4;                                  \
    GLD_LDS16(sp_, (char*)(QS) + i_*1024);                                     \
  }

#define QREAD(RD, QS)                                                          \
  _Pragma("unroll")                                                            \
  for (int p_ = 0; p_ < 2; ++p_) {                                             \
    f16x8 tmp_;                                                                \
    _Pragma("unroll")                                                          \
    for (int j_ = 0; j_ < 8; ++j_)                                             \
      tmp_[j_] = (_Float16)(SCALE * (QS)[(p_*16 + hi*8 + j_)*32 + colL]);      \
    qf[(RD)*2 + p_] = tmp_;                                                    \
  }

// duplicate read: accumulate all 8 lanes into qsum (keeps every LDS read live)
#define QREAD2(RD, QS)                                                         \
  _Pragma("unroll")                                                            \
  for (int p_ = 0; p_ < 2; ++p_) {                                             \
    _Pragma("unroll")                                                          \
    for (int j_ = 0; j_ < 8; ++j_)                                             \
      qsum += SCALE * (QS)[(p_*16 + hi*8 + j_)*32 + colL];                     \
  }

#define KSTAGE(TI, DST)                                                        \
  GLD_LDS16(kh + ((size_t)(TI)*4096 + (wid*64 + lane)*8),                      \
            (DST) + (size_t)(wid*64)*8);                                       \
  GLD_LDS16(kh + ((size_t)(TI)*4096 + (256 + wid*64 + lane)*8),                \
            (DST) + (size_t)(256 + wid*64)*8);

template<int MODE>
__global__ __launch_bounds__(256, 4) void attn_probe(
    const float* __restrict__ x, const _Float16* __restrict__ K16f,
    const float* __restrict__ K32, const float* __restrict__ V,
    float* __restrict__ out, float* __restrict__ idxf)
{
    __shared__ __align__(16) char smem[32768 + 2048];
    _Float16* bufA = (_Float16*)smem;
    _Float16* bufB = (_Float16*)(smem + 16384);
    float*    qbuf = (float*)(smem + 32768);

    const int t = threadIdx.x;
    const int wid = t >> 6, lane = t & 63;
    const int bid = blockIdx.x;
    const int h  = bid & 7;
    const int rr_ = bid >> 3;
    const int lx = rr_ & 31, b = rr_ >> 5;
    const int l0w = lx * 128 + wid * 32;

    const float* xb = x + ((size_t)(b*1024 + h*128)) * L_;
    const int colL = lane & 31;
    const int hi = lane >> 5;
    const int laneN4 = hi * 4;

    // ======= q phase =======
    float* qs0 = (float*)(smem + wid * 8192);
    float* qs1 = (float*)(smem + wid * 8192 + 4096);
    f16x8 qf[8];
    QSTAGE(0, qs0)
    QSTAGE(1, qs1)
    WAIT_VM0;
    QREAD(0, qs0)
    QREAD(1, qs1)
    WAIT_LGKM;
    QSTAGE(2, qs0)
    QSTAGE(3, qs1)
    WAIT_VM0;
    QREAD(2, qs0)
    QREAD(3, qs1)
    if constexpr (MODE == 1) {   // ---- q-phase x2
        float qsum = 0.f;
        WAIT_LGKM;
        QSTAGE(0, qs0)
        QSTAGE(1, qs1)
        WAIT_VM0;
        QREAD2(0, qs0)
        QREAD2(1, qs1)
        WAIT_LGKM;
        QSTAGE(2, qs0)
        QSTAGE(3, qs1)
        WAIT_VM0;
        QREAD2(2, qs0)
        QREAD2(3, qs1)
        asm volatile("" :: "v"(qsum));
    }
    __syncthreads();

    // ======= K loop: 8 periods x 2 tiles (R11 verbatim structure) =======
    const _Float16* kh = K16f + ((size_t)h << 16);

    KSTAGE(0, bufA)
    KSTAGE(1, bufA + 4096)

    float v1 = -INFINITY, v2 = -INFINITY, v3 = -INFINITY;
    int i1 = 0, i2 = 0;
    float v1b = -INFINITY, v2b = -INFINITY, v3b = -INFINITY;   // MODE 4 dup
    int i1b = 0, i2b = 0;
    float ksum = 0.f;                                          // MODE 2 dup
    float msum = 0.f;                                          // MODE 3 dup

    __syncthreads();

    for (int m = 0; m < 8; ++m) {
        _Float16* cur = (m & 1) ? bufB : bufA;
        _Float16* nxt = (m & 1) ? bufA : bufB;
        if (m < 7) {
            KSTAGE(2*m + 2, nxt)
            KSTAGE(2*m + 3, nxt + 4096)
        }
        #pragma unroll
        for (int sub = 0; sub < 2; ++sub) {
            const _Float16* kt = cur + sub*4096;
            f32x16 acc;
            #pragma unroll
            for (int r = 0; r < 16; ++r) acc[r] = 0.f;
            f32x16 acc2;
            if constexpr (MODE == 3) {
                #pragma unroll
                for (int r = 0; r < 16; ++r) acc2[r] = 0.f;
            }
            #pragma unroll
            for (int ds = 0; ds < 8; ++ds) {
                f16x8 kf = *(const f16x8*)(kt + (size_t)(ds*64 + lane)*8);
                acc = __builtin_amdgcn_mfma_f32_32x32x16_f16(kf, qf[ds], acc, 0, 0, 0);
                if constexpr (MODE == 2) {   // ---- ds_read x2 (lane^1: no CSE)
                    f16x8 kf2 = *(const f16x8*)(kt + (size_t)(ds*64 + (lane^1))*8);
                    ksum += (float)kf2[0] + (float)kf2[7];
                }
                if constexpr (MODE == 3) {   // ---- MFMA x2
                    acc2 = __builtin_amdgcn_mfma_f32_32x32x16_f16(kf, qf[ds], acc2, 0, 0, 0);
                }
            }
            if constexpr (MODE == 3) {
                #pragma unroll
                for (int r = 0; r < 16; ++r) msum += acc2[r];
            }
            const int nb = (2*m + sub)*32 + laneN4;
            #pragma unroll
            for (int r = 0; r < 16; ++r) {
                const int n = nb + (r & 3) + ((r >> 2) << 3);
                float v = acc[r];
                bool gt1 = v > v1;
                bool gt2 = v > v2;
                i2 = gt1 ? i1 : (gt2 ? n : i2);
                i1 = gt1 ? n  : i1;
                v3 = fmaxf(v3, fminf(v2, v));
                v2 = fmaxf(v2, fminf(v1, v));
                v1 = fmaxf(v1, v);
                if constexpr (MODE == 4) {   // ---- top-3 x2 (v+0.5: no CSE)
                    float w = v + 0.5f;
                    bool g1 = w > v1b;
                    bool g2 = w > v2b;
                    i2b = g1 ? i1b : (g2 ? n : i2b);
                    i1b = g1 ? n   : i1b;
                    v3b = fmaxf(v3b, fminf(v2b, w));
                    v2b = fmaxf(v2b, fminf(v1b, w));
                    v1b = fmaxf(v1b, w);
                }
            }
        }
        __syncthreads();
    }
    if constexpr (MODE == 2) asm volatile("" :: "v"(ksum));
    if constexpr (MODE == 3) asm volatile("" :: "v"(msum));
    if constexpr (MODE == 4) {
        float f1 = (float)i1b, f2 = (float)i2b;
        asm volatile("" :: "v"(v1b), "v"(v2b), "v"(v3b), "v"(f1), "v"(f2));
    }

    // ---- merge lane^32 halves (verified)
    float ov1 = __shfl_xor(v1, 32), ov2 = __shfl_xor(v2, 32), ov3 = __shfl_xor(v3, 32);
    int oi1 = __shfl_xor(i1, 32), oi2 = __shfl_xor(i2, 32);
    bool sw = (ov1 > v1) || (ov1 == v1 && oi1 < i1);
    float a1 = sw ? ov1 : v1;  int ai1 = sw ? oi1 : i1;
    float b1 = sw ? v1 : ov1;  int bi1 = sw ? i1 : oi1;
    float a2 = sw ? ov2 : v2;  int ai2 = sw ? oi2 : i2;
    float b2 = sw ? v2 : ov2;
    float a3 = sw ? ov3 : v3;
    bool sec = (b1 > a2) || (b1 == a2 && bi1 < ai2);
    const float V1 = a1;             const int I1 = ai1;
    const float V2 = sec ? b1 : a2;  const int I2 = sec ? bi1 : ai2;
    const float V3 = sec ? fmaxf(a2, b2) : fmaxf(a3, b1);
    int idx = I1;

    const bool cheap = (V1 - V2 < TAU) && (V1 - V3 >= TAU);
    const bool full  = (V1 - V3 < TAU);

    // ---- tier 1 (verified)
    unsigned long long mc = __ballot(cheap) & 0xffffffffull;
    while (mc) {
        int src = (int)__builtin_ctzll(mc); mc &= mc - 1;
        int rl = l0w + src;
        int ra = __shfl(I1, src);
        int rb = __shfl(I2, src);
        int n = hi ? rb : ra;
        f32x4 kk = *(const f32x4*)(K32 + ((size_t)(h*NC_ + n))*D_ + colL*4);
        int dd = colL * 4;
        float q0 = SCALE * xb[(size_t)(dd+0)*L_ + rl];
        float q1 = SCALE * xb[(size_t)(dd+1)*L_ + rl];
        float q2 = SCALE * xb[(size_t)(dd+2)*L_ + rl];
        float q3 = SCALE * xb[(size_t)(dd+3)*L_ + rl];
        float p = q0 * kk[0];
        p = fmaf(q1, kk[1], p); p = fmaf(q2, kk[2], p); p = fmaf(q3, kk[3], p);
        #pragma unroll
        for (int m2 = 1; m2 < 32; m2 <<= 1) p += __shfl_xor(p, m2);
        float va = __shfl(p, 0);
        float vb = __shfl(p, 32);
        bool takeB = (vb > va) || (vb == va && rb < ra);
        int win = takeB ? rb : ra;
        if (lane == src) idx = win;
    }

    // ---- tier 2 (verified coalesced)
    unsigned long long mf2 = __ballot(full) & 0xffffffffull;
    float* qb = qbuf + wid * 128;
    while (mf2) {
        int src = (int)__builtin_ctzll(mf2); mf2 &= mf2 - 1;
        int rl = l0w + src;
        qb[lane]      = SCALE * xb[(size_t)lane*L_ + rl];
        qb[lane + 64] = SCALE * xb[(size_t)(lane+64)*L_ + rl];
        __builtin_amdgcn_wave_barrier();
        WAIT_LGKM;
        float q0 = qb[colL*4+0], q1 = qb[colL*4+1], q2 = qb[colL*4+2], q3 = qb[colL*4+3];
        const f32x4* krow = (const f32x4*)(K32 + (size_t)h*NC_*D_);
        float bv = -INFINITY; int bn = 0;
        for (int i = 0; i < 256; i += 4) {
            #pragma unroll
            for (int u = 0; u < 4; ++u) {
                f32x4 kk = krow[(size_t)(i+u)*64 + lane];
                float p = q0 * kk[0];
                p = fmaf(q1, kk[1], p); p = fmaf(q2, kk[2], p); p = fmaf(q3, kk[3], p);
                #pragma unroll
                for (int m2 = 1; m2 < 32; m2 <<= 1) p += __shfl_xor(p, m2);
                const int n = 2*(i+u) + hi;
                if (p > bv) { bv = p; bn = n; }
            }
        }
        {
            float ov = __shfl_xor(bv, 32);
            int on = __shfl_xor(bn, 32);
            if (ov > bv || (ov == bv && on < bn)) { bv = ov; bn = on; }
        }
        if (lane == src) idx = bn;
        __builtin_amdgcn_wave_barrier();
    }
    idx = __shfl(idx, colL);

    // ---- outputs (verified)
    const int myl = l0w + colL;
    if (!hi) idxf[((size_t)(b*H_ + h))*L_ + myl] = (float)idx;
    const f32x4* vrow = (const f32x4*)(V + ((size_t)(h*NC_ + idx))*D_);
    float* ob = out + ((size_t)(b*1024 + h*128 + hi*64))*L_ + myl;
    #pragma unroll
    for (int p = 0; p < 16; ++p) {
        f32x4 vv = vrow[hi*16 + p];
        ob[(size_t)(p*4+0)*L_] = vv[0];
        ob[(size_t)(p*4+1)*L_] = vv[1];
        ob[(size_t)(p*4+2)*L_] = vv[2];
        ob[(size_t)(p*4+3)*L_] = vv[3];
    }
    if constexpr (MODE == 5) {   // ---- epilogue x2: same pattern, shifted h
        // slice (healed by the final MODE-0 kernel overwriting all of out)
        float* ob2 = out + ((size_t)(b*1024 + (((h+1)&7))*128 + hi*64))*L_ + myl;
        #pragma unroll
        for (int p = 0; p < 16; ++p) {
            f32x4 vv = vrow[hi*16 + p];
            ob2[(size_t)(p*4+0)*L_] = vv[0];
            ob2[(size_t)(p*4+1)*L_] = vv[1];
            ob2[(size_t)(p*4+2)*L_] = vv[2];
            ob2[(size_t)(p*4+3)*L_] = vv[3];
        }
    }
}

extern "C" void kernel_launch(void* const* d_in, const int* in_sizes, int n_in,
                              void* d_out, int out_size, void* d_ws, size_t ws_size,
                              hipStream_t stream)
{
    const float* x     = (const float*)d_in[0];
    const float* codes = (const float*)d_in[1];
    const float* Wk    = (const float*)d_in[2];
    const float* Wv    = (const float*)d_in[3];

    float* out  = (float*)d_out;
    float* idxf = out + (size_t)B_ * H_ * D_ * L_;

    _Float16* K16f = (_Float16*)d_ws;                        // 1 MB
    float*    K32  = (float*)((char*)d_ws + (1u << 20));     // 2 MB
    float*    Vf   = (float*)((char*)d_ws + (3u << 20));     // 2 MB

    kv_pre<<<dim3(32, 8, 2), 256, 0, stream>>>(codes, Wk, Wv, K16f, K32, Vf);
    // duplication probes (each writes correct out/idxf; MODE5's shifted-slice
    // writes are healed by the final MODE-0 kernel)
    attn_probe<1><<<dim3(1024), 256, 0, stream>>>(x, K16f, K32, Vf, out, idxf);
    attn_probe<2><<<dim3(1024), 256, 0, stream>>>(x, K16f, K32, Vf, out, idxf);
    attn_probe<3><<<dim3(1024), 256, 0, stream>>>(x, K16f, K32, Vf, out, idxf);
    attn_probe<4><<<dim3(1024), 256, 0, stream>>>(x, K16f, K32, Vf, out, idxf);
    attn_probe<5><<<dim3(1024), 256, 0, stream>>>(x, K16f, K32, Vf, out, idxf);
    // the real kernel, last
    attn_probe<0><<<dim3(1024), 256, 0, stream>>>(x, K16f, K32, Vf, out, idxf);
}

// Round 13
// 101.198 us; speedup vs baseline: 4.7602x; 4.7602x over previous
//
#include <hip/hip_runtime.h>
#include <cstdint>

#define L_ 4096
#define NC_ 512
#define CD_ 256
#define H_ 8
#define D_ 128
#define B_ 4
#define SCALE 0.08838834764831845f
#define TAU 4.0e-3f

typedef _Float16 f16x8 __attribute__((ext_vector_type(8)));
typedef _Float16 f16x4 __attribute__((ext_vector_type(4)));
typedef float f32x16 __attribute__((ext_vector_type(16)));
typedef float f32x4 __attribute__((ext_vector_type(4)));

// ---------------------------------------------------------------------------
// Kernel A (R11 structure): d-split grid dim3(32,8,2). ONE change: SCALE is
// folded into K16f (fp16 path only; K32 stays unscaled for exact repairs).
// ---------------------------------------------------------------------------
__global__ __launch_bounds__(256) void kv_pre(
    const float* __restrict__ codes, const float* __restrict__ Wk,
    const float* __restrict__ Wv, _Float16* __restrict__ K16f,
    float* __restrict__ K32, float* __restrict__ V)
{
    __shared__ float clds[16][260];
    const int t = threadIdx.x, h = blockIdx.y, n0 = blockIdx.x * 16;
    const int dz = blockIdx.z;
    {
        #pragma unroll
        for (int i = 0; i < 4; ++i) {
            int j = t + i*256;
            int row = j >> 6, c4 = j & 63;
            *(float4*)&clds[row][c4*4] =
                *(const float4*)(codes + (size_t)(n0 + row)*CD_ + c4*4);
        }
    }
    __syncthreads();
    const int nl = t >> 4;
    const int dq = t & 15;
    const int d0 = dz*64 + dq*4;
    const int n  = n0 + nl;
    float ak0=0,ak1=0,ak2=0,ak3=0, av0=0,av1=0,av2=0,av3=0;
    const float4* wk4 = (const float4*)Wk;
    const float4* wv4 = (const float4*)Wv;
    for (int c = 0; c < CD_; c += 4) {
        float4 cv = *(const float4*)&clds[nl][c];
        #pragma unroll
        for (int u = 0; u < 4; ++u) {
            float cu = (u==0)?cv.x:(u==1)?cv.y:(u==2)?cv.z:cv.w;
            float4 wk = wk4[((size_t)(c+u)*H_ + h)*32 + (d0>>2)];
            float4 wv = wv4[((size_t)(c+u)*H_ + h)*32 + (d0>>2)];
            ak0 = fmaf(cu, wk.x, ak0); ak1 = fmaf(cu, wk.y, ak1);
            ak2 = fmaf(cu, wk.z, ak2); ak3 = fmaf(cu, wk.w, ak3);
            av0 = fmaf(cu, wv.x, av0); av1 = fmaf(cu, wv.y, av1);
            av2 = fmaf(cu, wv.z, av2); av3 = fmaf(cu, wv.w, av3);
        }
    }
    const size_t r32 = ((size_t)(h*NC_ + n))*D_ + d0;
    float4 sk; sk.x=ak0; sk.y=ak1; sk.z=ak2; sk.w=ak3;
    float4 sv; sv.x=av0; sv.y=av1; sv.z=av2; sv.w=av3;
    *(float4*)(K32 + r32) = sk;
    *(float4*)(V   + r32) = sv;
    // SCALE folded into the fp16 MFMA operand
    f16x4 hk;
    hk[0]=(_Float16)(SCALE*ak0); hk[1]=(_Float16)(SCALE*ak1);
    hk[2]=(_Float16)(SCALE*ak2); hk[3]=(_Float16)(SCALE*ak3);
    const size_t a16 = ((size_t)((h*16 + (n>>5))*8 + (d0>>4))*64
                        + ((n&31) + ((d0>>3)&1)*32))*8 + (d0&7);
    *(f16x4*)(K16f + a16) = hk;
}

// ---------------------------------------------------------------------------
// Kernel B: R11 verified structure + index-packed-key top-3 (7 VALU ops/logit,
// no index select chains). TAU widened to absorb key truncation (<=512 ulp).
// ---------------------------------------------------------------------------
#define GLD_LDS16(GP, LP)                                                      \
  __builtin_amdgcn_global_load_lds(                                            \
      (const __attribute__((address_space(1))) void*)(GP),                     \
      (__attribute__((address_space(3))) void*)(LP), 16, 0, 0)

#define WAIT_VM0    asm volatile("s_waitcnt vmcnt(0)" ::: "memory")
#define WAIT_LGKM   asm volatile("s_waitcnt lgkmcnt(0)" ::: "memory")

#define QSTAGE(RD, QS)                                                         \
  _Pragma("unroll")                                                            \
  for (int i_ = 0; i_ < 4; ++i_) {                                             \
    const float* sp_ = xb + (size_t)((RD)*32 + i_*8 + (lane>>3))*L_            \
                          + l0w + (lane&7)*4;                                  \
    GLD_LDS16(sp_, (char*)(QS) + i_*1024);                                     \
  }

// SCALE now lives in K16f; q converts raw x to fp16
#define QREAD(RD, QS)                                                          \
  _Pragma("unroll")                                                            \
  for (int p_ = 0; p_ < 2; ++p_) {                                             \
    f16x8 tmp_;                                                                \
    _Pragma("unroll")                                                          \
    for (int j_ = 0; j_ < 8; ++j_)                                             \
      tmp_[j_] = (_Float16)((QS)[(p_*16 + hi*8 + j_)*32 + colL]);              \
    qf[(RD)*2 + p_] = tmp_;                                                    \
  }

#define KSTAGE(TI, DST)                                                        \
  GLD_LDS16(kh + ((size_t)(TI)*4096 + (wid*64 + lane)*8),                      \
            (DST) + (size_t)(wid*64)*8);                                       \
  GLD_LDS16(kh + ((size_t)(TI)*4096 + (256 + wid*64 + lane)*8),                \
            (DST) + (size_t)(256 + wid*64)*8);

__global__ __launch_bounds__(256, 4) void attn_main(
    const float* __restrict__ x, const _Float16* __restrict__ K16f,
    const float* __restrict__ K32, const float* __restrict__ V,
    float* __restrict__ out, float* __restrict__ idxf)
{
    __shared__ __align__(16) char smem[32768 + 2048];
    _Float16* bufA = (_Float16*)smem;             // 16 KB (2 tiles)
    _Float16* bufB = (_Float16*)(smem + 16384);   // 16 KB (2 tiles)
    float*    qbuf = (float*)(smem + 32768);      // 4 x 128 floats (repair)

    const int t = threadIdx.x;
    const int wid = t >> 6, lane = t & 63;
    const int bid = blockIdx.x;
    const int h  = bid & 7;              // head-per-XCD affinity
    const int rr_ = bid >> 3;
    const int lx = rr_ & 31, b = rr_ >> 5;
    const int l0w = lx * 128 + wid * 32;

    const float* xb = x + ((size_t)(b*1024 + h*128)) * L_;
    const int colL = lane & 31;
    const int hi = lane >> 5;
    const int laneN4 = hi * 4;

    // ======= q phase: per-wave DMA transpose, full drains (verified) =======
    float* qs0 = (float*)(smem + wid * 8192);
    float* qs1 = (float*)(smem + wid * 8192 + 4096);
    f16x8 qf[8];
    QSTAGE(0, qs0)
    QSTAGE(1, qs1)
    WAIT_VM0;
    QREAD(0, qs0)
    QREAD(1, qs1)
    WAIT_LGKM;
    QSTAGE(2, qs0)
    QSTAGE(3, qs1)
    WAIT_VM0;
    QREAD(2, qs0)
    QREAD(3, qs1)
    __syncthreads();      // qstage dead; reuse LDS as K buffers

    // ======= K loop: 8 periods x 2 tiles, full-drain per period (verified) ==
    const _Float16* kh = K16f + ((size_t)h << 16);

    KSTAGE(0, bufA)
    KSTAGE(1, bufA + 4096)

    // key-packed top-3: key = (bits(v) & ~0x1FF) | n  — no index registers
    int nOr[16];
    #pragma unroll
    for (int r = 0; r < 16; ++r) nOr[r] = (r & 3) + ((r >> 2) << 3) + laneN4;
    float v1 = -INFINITY, v2 = -INFINITY, v3 = -INFINITY;

    __syncthreads();      // tiles 0,1 staged

    for (int m = 0; m < 8; ++m) {
        _Float16* cur = (m & 1) ? bufB : bufA;
        _Float16* nxt = (m & 1) ? bufA : bufB;
        if (m < 7) {
            KSTAGE(2*m + 2, nxt)
            KSTAGE(2*m + 3, nxt + 4096)
        }
        #pragma unroll
        for (int sub = 0; sub < 2; ++sub) {
            const _Float16* kt = cur + sub*4096;
            f32x16 acc;
            #pragma unroll
            for (int r = 0; r < 16; ++r) acc[r] = 0.f;
            #pragma unroll
            for (int ds = 0; ds < 8; ++ds) {
                f16x8 kf = *(const f16x8*)(kt + (size_t)(ds*64 + lane)*8);
                acc = __builtin_amdgcn_mfma_f32_32x32x16_f16(kf, qf[ds], acc, 0, 0, 0);
            }
            const int tb = (2*m + sub)*32;
            #pragma unroll
            for (int r = 0; r < 16; ++r) {
                int ki = (__float_as_int(acc[r]) & 0xFFFFFE00) | (tb + nOr[r]);
                float k = __int_as_float(ki);
                v3 = fmaxf(v3, fminf(fminf(v1, v2), k));   // max(v3, min3(v1,v2,k))
                float nv2 = __builtin_amdgcn_fmed3f(v1, v2, k);
                v1 = fmaxf(v1, k);
                v2 = nv2;
            }
        }
        __syncthreads();
    }

    // ---- merge lane^32 halves on keys (3 shuffles, no index logic)
    float b1k = __shfl_xor(v1, 32);
    float b2k = __shfl_xor(v2, 32);
    float b3k = __shfl_xor(v3, 32);
    const float V1 = fmaxf(v1, b1k);
    const float c1 = fminf(v1, b1k);
    const float d1 = fmaxf(v2, b2k);
    const float V2 = fmaxf(c1, d1);
    const float V3 = __builtin_amdgcn_fmed3f(c1, d1, fmaxf(v3, b3k));
    const int I1 = __float_as_int(V1) & 511;
    const int I2 = __float_as_int(V2) & 511;
    int idx = I1;

    const bool cheap = (V1 - V2 < TAU) && (V1 - V3 >= TAU);
    const bool full  = (V1 - V3 < TAU);

    // ---- tier 1: cheap repair — exact fp32 dots for the two candidates only
    unsigned long long mc = __ballot(cheap) & 0xffffffffull;
    while (mc) {
        int src = (int)__builtin_ctzll(mc); mc &= mc - 1;
        int rl = l0w + src;
        int ra = __shfl(I1, src);
        int rb = __shfl(I2, src);
        int n = hi ? rb : ra;
        f32x4 kk = *(const f32x4*)(K32 + ((size_t)(h*NC_ + n))*D_ + colL*4);
        int dd = colL * 4;
        float q0 = SCALE * xb[(size_t)(dd+0)*L_ + rl];
        float q1 = SCALE * xb[(size_t)(dd+1)*L_ + rl];
        float q2 = SCALE * xb[(size_t)(dd+2)*L_ + rl];
        float q3 = SCALE * xb[(size_t)(dd+3)*L_ + rl];
        float p = q0 * kk[0];
        p = fmaf(q1, kk[1], p); p = fmaf(q2, kk[2], p); p = fmaf(q3, kk[3], p);
        #pragma unroll
        for (int m2 = 1; m2 < 32; m2 <<= 1) p += __shfl_xor(p, m2);
        float va = __shfl(p, 0);
        float vb = __shfl(p, 32);
        bool takeB = (vb > va) || (vb == va && rb < ra);
        int win = takeB ? rb : ra;
        if (lane == src) idx = win;
    }

    // ---- tier 2: full exact rescan, coalesced row-pair form (verified)
    unsigned long long mf2 = __ballot(full) & 0xffffffffull;
    float* qb = qbuf + wid * 128;
    while (mf2) {
        int src = (int)__builtin_ctzll(mf2); mf2 &= mf2 - 1;
        int rl = l0w + src;
        qb[lane]      = SCALE * xb[(size_t)lane*L_ + rl];
        qb[lane + 64] = SCALE * xb[(size_t)(lane+64)*L_ + rl];
        __builtin_amdgcn_wave_barrier();
        WAIT_LGKM;
        float q0 = qb[colL*4+0], q1 = qb[colL*4+1], q2 = qb[colL*4+2], q3 = qb[colL*4+3];
        const f32x4* krow = (const f32x4*)(K32 + (size_t)h*NC_*D_);
        float bv = -INFINITY; int bn = 0;
        for (int i = 0; i < 256; i += 4) {
            #pragma unroll
            for (int u = 0; u < 4; ++u) {
                f32x4 kk = krow[(size_t)(i+u)*64 + lane];   // row 2(i+u)+hi
                float p = q0 * kk[0];
                p = fmaf(q1, kk[1], p); p = fmaf(q2, kk[2], p); p = fmaf(q3, kk[3], p);
                #pragma unroll
                for (int m2 = 1; m2 < 32; m2 <<= 1) p += __shfl_xor(p, m2);
                const int n = 2*(i+u) + hi;
                if (p > bv) { bv = p; bn = n; }
            }
        }
        {
            float ov = __shfl_xor(bv, 32);
            int on = __shfl_xor(bn, 32);
            if (ov > bv || (ov == bv && on < bn)) { bv = ov; bn = on; }
        }
        if (lane == src) idx = bn;
        __builtin_amdgcn_wave_barrier();
    }
    idx = __shfl(idx, colL);   // broadcast repaired idx to the hi-half lane

    // ---- outputs: idx (as float, lanes 0-31) + fused V gather (d split by hi)
    const int myl = l0w + colL;
    if (!hi) idxf[((size_t)(b*H_ + h))*L_ + myl] = (float)idx;
    const f32x4* vrow = (const f32x4*)(V + ((size_t)(h*NC_ + idx))*D_);
    float* ob = out + ((size_t)(b*1024 + h*128 + hi*64))*L_ + myl;
    #pragma unroll
    for (int p = 0; p < 16; ++p) {
        f32x4 vv = vrow[hi*16 + p];
        ob[(size_t)(p*4+0)*L_] = vv[0];
        ob[(size_t)(p*4+1)*L_] = vv[1];
        ob[(size_t)(p*4+2)*L_] = vv[2];
        ob[(size_t)(p*4+3)*L_] = vv[3];
    }
}

extern "C" void kernel_launch(void* const* d_in, const int* in_sizes, int n_in,
                              void* d_out, int out_size, void* d_ws, size_t ws_size,
                              hipStream_t stream)
{
    const float* x     = (const float*)d_in[0];
    const float* codes = (const float*)d_in[1];
    const float* Wk    = (const float*)d_in[2];
    const float* Wv    = (const float*)d_in[3];

    float* out  = (float*)d_out;
    float* idxf = out + (size_t)B_ * H_ * D_ * L_;

    _Float16* K16f = (_Float16*)d_ws;                        // 1 MB
    float*    K32  = (float*)((char*)d_ws + (1u << 20));     // 2 MB
    float*    Vf   = (float*)((char*)d_ws + (3u << 20));     // 2 MB

    kv_pre<<<dim3(32, 8, 2), 256, 0, stream>>>(codes, Wk, Wv, K16f, K32, Vf);
    attn_main<<<dim3(1024), 256, 0, stream>>>(x, K16f, K32, Vf, out, idxf);
}